// Round 3
// baseline (239.914 us; speedup 1.0000x reference)
//
#include <hip/hip_runtime.h>
#include <math.h>

#define WPB 4  // waves per block (block = 256 threads)

// Fused per-bit rotation (see derivation in earlier rounds):
//   qubit n acts on global bit b = 9-n, theta_b = 0.5*sum_{l,k} ang[l][n][3].
//   Layers fuse (2D rotations on the same bit compose by angle addition) and
//   cnot_matrix is the identity permutation.
//
// Layout (held end-to-end, loads AND stores coalesced float4):
//   element i = 256*m + 4*lane + k  ->  v[4*m+k]
//   reg bits {0,1}=k, {8,9}=m  -> in-register butterflies
//   lane bits: global bits 2..7 = lane bits 0..5:
//     xor1  -> DPP quad_perm [1,0,3,2]      (VALU pipe)
//     xor2  -> DPP quad_perm [2,3,0,1]      (VALU pipe)
//     xor4  -> ds_swizzle XOR mode          (only DS-pipe op left)
//     xor8  -> DPP row_ror:8  (rot by half-group == xor top bit)
//     xor16 -> permlane16_swap               (VALU pipe)
//     xor32 -> permlane32_swap               (VALU pipe)
// Ping-pong prefetch (A/B reg buffers) hides HBM latency under the
// per-row compute chain. No __shared__, no barriers, no asm sched walls.

#define DPP_XOR1 0xB1   // quad_perm [1,0,3,2]
#define DPP_XOR2 0x4E   // quad_perm [2,3,0,1]
#define DPP_XOR8 0x128  // row_ror:8

template <int CTRL>
__device__ __forceinline__ float fdpp(float v) {
    return __int_as_float(
        __builtin_amdgcn_mov_dpp(__float_as_int(v), CTRL, 0xF, 0xF, false));
}

__global__ __launch_bounds__(256) void qel_dpp(
    const float* __restrict__ x,
    const float* __restrict__ ang,   // [4][10][3]
    float* __restrict__ out,
    int rows)
{
    const int tid  = threadIdx.x;
    const int lane = tid & 63;

    float cb[10], sb[10];
#pragma unroll
    for (int n = 0; n < 10; ++n) {
        float t = 0.f;
#pragma unroll
        for (int l = 0; l < 4; ++l) {
            const float* a = ang + (l * 10 + n) * 3;
            t += a[0] + a[1] + a[2];
        }
        t *= 0.5f;
        sincosf(t, &sb[9 - n], &cb[9 - n]);
    }

    // Signed sine for lane-bit stages B=0..5 (partner-select form):
    //   bit==0: v' = c*v - s*p ; bit==1: v' = s*p + c*v  ->  v' = fma(c,v,se*p)
    float se[6];
#pragma unroll
    for (int B = 0; B < 6; ++B)
        se[B] = ((lane >> B) & 1) ? sb[B + 2] : -sb[B + 2];

    // (alpha,beta) form for the permlane-swap stages: the builtin returns
    //   r0 = (bit ? partner : self), r1 = (bit ? self : partner)
    // so uniformly v' = alpha*r0 + beta*r1 with
    //   bit==0: alpha=c, beta=-s ;  bit==1: alpha=s, beta=c.
    const float a16 = (lane & 16) ? sb[6] : cb[6];
    const float b16 = (lane & 16) ? cb[6] : -sb[6];
    const float a32 = (lane & 32) ? sb[7] : cb[7];
    const float b32 = (lane & 32) ? cb[7] : -sb[7];

    const int waveId = blockIdx.x * WPB + (tid >> 6);
    const int nW     = gridDim.x * WPB;

#define LOADROW(V, R)                                                       \
    do {                                                                    \
        const float* xr_ = x + (size_t)(R) * 1024;                          \
        _Pragma("unroll")                                                   \
        for (int m = 0; m < 4; ++m) {                                       \
            const float4 t4 = *(const float4*)(xr_ + 256 * m + 4 * lane);   \
            V[4*m+0]=t4.x; V[4*m+1]=t4.y; V[4*m+2]=t4.z; V[4*m+3]=t4.w;     \
        }                                                                   \
    } while (0)

#define RSTAGE(V, P, CC, SS)                                                \
    do {                                                                    \
        _Pragma("unroll")                                                   \
        for (int q = 0; q < 16; ++q)                                        \
            if ((q & (1 << (P))) == 0) {                                    \
                const float lo = V[q], hi = V[q | (1 << (P))];              \
                V[q]              = (CC) * lo - (SS) * hi;                  \
                V[q | (1 << (P))] = (SS) * lo + (CC) * hi;                  \
            }                                                               \
    } while (0)

#define DPPSTAGE(V, CTRL, CC, SE)                                           \
    do {                                                                    \
        float p_[16];                                                       \
        _Pragma("unroll")                                                   \
        for (int q = 0; q < 16; ++q) p_[q] = fdpp<CTRL>(V[q]);              \
        _Pragma("unroll")                                                   \
        for (int q = 0; q < 16; ++q)                                        \
            V[q] = fmaf((CC), V[q], (SE) * p_[q]);                          \
    } while (0)

#define DSSTAGE(V, IMM, CC, SE)                                             \
    do {                                                                    \
        float p_[16];                                                       \
        _Pragma("unroll")                                                   \
        for (int q = 0; q < 16; ++q)                                        \
            p_[q] = __int_as_float(__builtin_amdgcn_ds_swizzle(             \
                        __float_as_int(V[q]), (IMM)));                      \
        _Pragma("unroll")                                                   \
        for (int q = 0; q < 16; ++q)                                        \
            V[q] = fmaf((CC), V[q], (SE) * p_[q]);                          \
    } while (0)

#if defined(__has_builtin) && __has_builtin(__builtin_amdgcn_permlane16_swap)
#define PL16STAGE(V)                                                        \
    do {                                                                    \
        _Pragma("unroll")                                                   \
        for (int q = 0; q < 16; ++q) {                                      \
            const int s_ = __float_as_int(V[q]);                            \
            auto r_ = __builtin_amdgcn_permlane16_swap(s_, s_, false, false);\
            V[q] = fmaf(a16, __int_as_float(r_[0]),                         \
                        b16 * __int_as_float(r_[1]));                       \
        }                                                                   \
    } while (0)
#else
#define PL16STAGE(V) DSSTAGE(V, 0x401F, cb[6], se[4])
#endif

#if defined(__has_builtin) && __has_builtin(__builtin_amdgcn_permlane32_swap)
#define PL32STAGE(V)                                                        \
    do {                                                                    \
        _Pragma("unroll")                                                   \
        for (int q = 0; q < 16; ++q) {                                      \
            const int s_ = __float_as_int(V[q]);                            \
            auto r_ = __builtin_amdgcn_permlane32_swap(s_, s_, false, false);\
            V[q] = fmaf(a32, __int_as_float(r_[0]),                         \
                        b32 * __int_as_float(r_[1]));                       \
        }                                                                   \
    } while (0)
#else
#define PL32STAGE(V)                                                        \
    do {                                                                    \
        float p_[16];                                                       \
        _Pragma("unroll")                                                   \
        for (int q = 0; q < 16; ++q) p_[q] = __shfl_xor(V[q], 32, 64);      \
        _Pragma("unroll")                                                   \
        for (int q = 0; q < 16; ++q)                                        \
            V[q] = fmaf(cb[7], V[q], se[5] * p_[q]);                        \
    } while (0)
#endif

#define PROCESS_STORE(V, R)                                                 \
    do {                                                                    \
        RSTAGE(V, 0, cb[0], sb[0]);   /* global bit 0 */                    \
        RSTAGE(V, 1, cb[1], sb[1]);   /* global bit 1 */                    \
        RSTAGE(V, 2, cb[8], sb[8]);   /* global bit 8 */                    \
        RSTAGE(V, 3, cb[9], sb[9]);   /* global bit 9 */                    \
        DPPSTAGE(V, DPP_XOR1, cb[2], se[0]);   /* bit 2 */                  \
        DPPSTAGE(V, DPP_XOR2, cb[3], se[1]);   /* bit 3 */                  \
        DSSTAGE (V, 0x101F,   cb[4], se[2]);   /* bit 4 (xor4, DS pipe) */  \
        DPPSTAGE(V, DPP_XOR8, cb[5], se[3]);   /* bit 5 */                  \
        PL16STAGE(V);                          /* bit 6 (xor16) */          \
        PL32STAGE(V);                          /* bit 7 (xor32) */          \
        float* yr_ = out + (size_t)(R) * 1024;                              \
        _Pragma("unroll")                                                   \
        for (int m = 0; m < 4; ++m) {                                       \
            const float4 t4 =                                               \
                make_float4(V[4*m+0], V[4*m+1], V[4*m+2], V[4*m+3]);        \
            *(float4*)(yr_ + 256 * m + 4 * lane) = t4;                      \
        }                                                                   \
    } while (0)

    // Ping-pong prefetch: next row's loads issue before current row's
    // compute chain -> HBM latency hides under ~900 cycles of VALU/DPP.
    int r0 = waveId;
    if (r0 >= rows) return;
    float A[16], B[16];
    LOADROW(A, r0);
    while (true) {
        int r1 = r0 + nW;
        if (r1 < rows) LOADROW(B, r1);
        PROCESS_STORE(A, r0);
        if (r1 >= rows) break;
        r0 = r1 + nW;
        if (r0 < rows) LOADROW(A, r0);
        PROCESS_STORE(B, r1);
        if (r0 >= rows) break;
    }

#undef LOADROW
#undef RSTAGE
#undef DPPSTAGE
#undef DSSTAGE
#undef PL16STAGE
#undef PL32STAGE
#undef PROCESS_STORE
}

extern "C" void kernel_launch(void* const* d_in, const int* in_sizes, int n_in,
                              void* d_out, int out_size, void* d_ws, size_t ws_size,
                              hipStream_t stream) {
    const float* x   = (const float*)d_in[0];
    const float* ang = (const float*)d_in[1];
    // d_in[2] (cnot_matrix) is provably the identity permutation -> unused.
    float* out = (float*)d_out;
    const int rows = in_sizes[0] / 1024;   // 32768
    int blocks = (rows + WPB - 1) / WPB;
    if (blocks > 2048) blocks = 2048;      // 8 blocks/CU, grid-stride (4 rows/wave)
    qel_dpp<<<blocks, 256, 0, stream>>>(x, ang, out, rows);
}